// Round 8
// baseline (736.418 us; speedup 1.0000x reference)
//
#include <hip/hip_runtime.h>
#include <hip/hip_bf16.h>

#define BN_EPS 1e-5f

typedef __attribute__((ext_vector_type(8))) short short8;
typedef __attribute__((ext_vector_type(4))) float f32x4;

__device__ __forceinline__ float bits2f(unsigned int u) {
    union { unsigned int i; float f; } c; c.i = u; return c.f;
}
__device__ __forceinline__ float b2f(unsigned short u) { return bits2f(((unsigned int)u) << 16); }
__device__ __forceinline__ unsigned short f2b(float v) {
    __hip_bfloat16 h = __float2bfloat16(v);
    union { __hip_bfloat16 h; unsigned short u; } c; c.h = h; return c.u;
}
__device__ __forceinline__ int clampi(int v, int hi) {
    return v < 0 ? 0 : (v >= hi ? hi - 1 : v);
}

// ---------------- setup / zero ----------------

__global__ void zero_f32(long long n, float* __restrict__ p) {
    long long i = (long long)blockIdx.x * blockDim.x + threadIdx.x;
    if (i < n) p[i] = 0.f;
}

__global__ void setup_zero(int N, int* __restrict__ degc, float* __restrict__ s1,
                           float* __restrict__ s2) {
    int i = blockIdx.x * blockDim.x + threadIdx.x;
    if (i <= N) degc[i] = 0;
    if (i < 256) { s1[i] = 0.f; s2[i] = 0.f; }
}

// ---------------- degree / CSR construction ----------------

__global__ void count_deg(int E, int N, const int* __restrict__ ei, int* __restrict__ degc) {
    int e = blockIdx.x * blockDim.x + threadIdx.x;
    if (e >= E) return;
    atomicAdd(&degc[clampi(ei[(size_t)E + e], N)], 1);
}

__global__ __launch_bounds__(256) void scan_block(int N, const int* __restrict__ cnts,
                                                  int* __restrict__ ex, int* __restrict__ bsum) {
    __shared__ int s[256];
    int t = threadIdx.x;
    int i = blockIdx.x * 256 + t;
    int v = (i < N) ? cnts[i] : 0;
    s[t] = v;
    __syncthreads();
    for (int o = 1; o < 256; o <<= 1) {
        int add = (t >= o) ? s[t - o] : 0;
        __syncthreads();
        s[t] += add;
        __syncthreads();
    }
    if (i < N) ex[i] = s[t] - v;
    if (t == 255) bsum[blockIdx.x] = s[255];
}

__global__ __launch_bounds__(1024) void scan_sums(int nb, const int* __restrict__ bsum,
                                                  int* __restrict__ boff) {
    __shared__ int s[1024];
    int t = threadIdx.x;
    int v = (t < nb) ? bsum[t] : 0;
    s[t] = v;
    __syncthreads();
    for (int o = 1; o < 1024; o <<= 1) {
        int add = (t >= o) ? s[t - o] : 0;
        __syncthreads();
        s[t] += add;
        __syncthreads();
    }
    if (t < nb) boff[t] = s[t] - v;
}

// also computes dis[i] = rsqrt(deg+1)
__global__ void finalize_rowptr(int N, int nb, const int* __restrict__ ex,
                                const int* __restrict__ boff, const int* __restrict__ bsum,
                                const int* __restrict__ degc,
                                int* __restrict__ row_ptr, int* __restrict__ cursor,
                                float* __restrict__ dis) {
    int i = blockIdx.x * blockDim.x + threadIdx.x;
    if (i < N) {
        int v = ex[i] + boff[i >> 8];
        row_ptr[i] = v;
        cursor[i]  = v;
        dis[i] = rsqrtf((float)degc[i] + 1.0f);
    } else if (i == N) {
        row_ptr[N] = boff[nb - 1] + bsum[nb - 1];
    }
}

__global__ void scatter_edges(int E, int N, const int* __restrict__ ei, const float* __restrict__ dis,
                              int* __restrict__ cursor, int* __restrict__ col,
                              float* __restrict__ wnorm) {
    int e = blockIdx.x * blockDim.x + threadIdx.x;
    if (e >= E) return;
    int s = clampi(ei[e], N);
    int d = clampi(ei[(size_t)E + e], N);
    int pos = atomicAdd(&cursor[d], 1);
    col[pos]   = s;
    wnorm[pos] = dis[s] * dis[d];
}

// ---------------- graph segment starts from sorted batch (replaces count+scan) ----------------

__global__ void graph_starts(int N, int G, const int* __restrict__ batch, int* __restrict__ gstart) {
    int i = blockIdx.x * blockDim.x + threadIdx.x;
    if (i > N) return;
    int curr = (i < N) ? clampi(batch[i], G) : G;
    int prev = (i > 0) ? clampi(batch[i - 1], G) : -1;
    for (int g = prev + 1; g <= curr; ++g) gstart[g] = i;
}

// ---------------- merged W swizzles (B-fragment order, bf16) ----------------
// Wz element ((kb*256 + n)*4 + quad)*8 + j = bf16( W[kb*32 + quad*8 + j][n] )

__device__ __forceinline__ void swz_one(int idx, const float* __restrict__ W,
                                        unsigned short* __restrict__ Wz) {
    int quad = idx & 3;
    int n    = (idx >> 2) & 255;
    int kb   = idx >> 10;
    unsigned short o[8];
#pragma unroll
    for (int j = 0; j < 8; ++j)
        o[j] = f2b(W[(size_t)(kb * 32 + quad * 8 + j) * 256 + n]);
    ushort4* dst = (ushort4*)(Wz + (size_t)idx * 8);
    dst[0] = make_ushort4(o[0], o[1], o[2], o[3]);
    dst[1] = make_ushort4(o[4], o[5], o[6], o[7]);
}

__global__ void swizzle_all(const float* __restrict__ W2, unsigned short* __restrict__ Wz2,
                            const float* __restrict__ W3, unsigned short* __restrict__ Wz3,
                            const float* __restrict__ Wp, unsigned short* __restrict__ Wzp) {
    int idx = blockIdx.x * blockDim.x + threadIdx.x;
    if (idx < 4096)        swz_one(idx, W2, Wz2);
    else if (idx < 12288)  swz_one(idx - 4096, W3, Wz3);
    else if (idx < 20480)  swz_one(idx - 12288, Wp, Wzp);
}

// ---------------- layer 1: fused CSR gather (9 ch) + GEMM 9->128 + stats ----------------

__global__ __launch_bounds__(256) void gemm9_fused(
    int n, const int* __restrict__ row_ptr, const int* __restrict__ col,
    const float* __restrict__ wnorm, const float* __restrict__ dis,
    const float* __restrict__ x, const float* __restrict__ W, const float* __restrict__ bias,
    __hip_bfloat16* __restrict__ y, float* __restrict__ part1, float* __restrict__ part2) {
    __shared__ float sW[9 * 128];
    __shared__ float sA[16 * 9];
    __shared__ float lds1[256];
    __shared__ float lds2[256];
    int t = threadIdx.x;
    long long row0 = (long long)blockIdx.x * 16;
    for (int idx = t; idx < 9 * 128; idx += 256) sW[idx] = W[idx];
    if (t < 144) {
        int r = t / 9;
        int k = t - r * 9;
        long long row = row0 + r;
        float a = 0.f;
        if (row < n) {
            float dd = dis[row];
            a = dd * dd * x[row * 9 + k];
            int e0 = row_ptr[row], e1 = row_ptr[row + 1];
            for (int e = e0; e < e1; ++e)
                a = fmaf(wnorm[e], x[(long long)col[e] * 9 + k], a);
        }
        sA[r * 9 + k] = a;
    }
    __syncthreads();
    int ch   = t & 127;
    int half = t >> 7;
    float bb = bias[ch];
    float s1p = 0.f, s2p = 0.f;
#pragma unroll
    for (int r8 = 0; r8 < 8; ++r8) {
        int r = half * 8 + r8;
        long long row = row0 + r;
        float acc = bb;
#pragma unroll
        for (int k = 0; k < 9; ++k) acc = fmaf(sA[r * 9 + k], sW[k * 128 + ch], acc);
        if (row < n) {
            y[row * 128 + ch] = __float2bfloat16(acc);
            s1p += acc;
            s2p += acc * acc;
        }
    }
    lds1[t] = s1p; lds2[t] = s2p;
    __syncthreads();
    if (t < 128) {
        part1[(size_t)blockIdx.x * 128 + t] = lds1[t] + lds1[t + 128];
        part2[(size_t)blockIdx.x * 128 + t] = lds2[t] + lds2[t + 128];
    }
}

// ---------------- fused CSR-gather + MFMA GEMM (Cout=256) + stats ----------------
// R rows/block, TPR=256/R threads/row, EPT=CIN/TPR=16 channels/thread (2x short8),
// edge loop unrolled x4 -> 8 outstanding 16B loads at ~70 VGPR.

template<int CIN, int R>
__global__ __launch_bounds__(256) void fused_agg_gemm_mfma(
    int n, const int* __restrict__ row_ptr, const int* __restrict__ col,
    const float* __restrict__ wnorm, const float* __restrict__ dis,
    const __hip_bfloat16* __restrict__ Aprev,
    const float* __restrict__ scale, const float* __restrict__ shift,
    const unsigned short* __restrict__ Wz, const float* __restrict__ bias,
    __hip_bfloat16* __restrict__ Anext,
    float* __restrict__ part1, float* __restrict__ part2) {
    constexpr int TPR = 256 / R;
    constexpr int EPT = CIN / TPR;        // 16
    constexpr int NL  = EPT / 8;          // 2
    constexpr int MT  = R / 16;
    constexpr int LDW = CIN + 8;
    __shared__ unsigned short As[R * LDW];
    __shared__ float ssc[CIN];
    __shared__ float ssh[CIN];
    int t = threadIdx.x;
    for (int c = t; c < CIN; c += 256) { ssc[c] = scale[c]; ssh[c] = shift[c]; }
    __syncthreads();

    int r  = t / TPR;
    int tr = t % TPR;
    int c0 = tr * EPT;
    long long row0 = (long long)blockIdx.x * R;
    long long dst  = row0 + r;

    float acc[EPT];
#pragma unroll
    for (int j = 0; j < EPT; ++j) acc[j] = 0.f;

    const unsigned short* base = (const unsigned short*)Aprev;

    if (dst < n) {
        auto apply = [&](const short8* b, float nm) {
#pragma unroll
            for (int l = 0; l < NL; ++l)
#pragma unroll
                for (int q = 0; q < 8; ++q) {
                    int j = l * 8 + q;
                    float v = b2f((unsigned short)b[l][q]);
                    acc[j] = fmaf(nm, fmaxf(fmaf(v, ssc[c0 + j], ssh[c0 + j]), 0.f), acc[j]);
                }
        };
        short8 buf[NL];
        {
            const unsigned short* ap = base + dst * CIN + c0;
#pragma unroll
            for (int l = 0; l < NL; ++l) buf[l] = ((const short8*)ap)[l];
            float dd = dis[dst];
            apply(buf, dd * dd);
        }
        int e0 = row_ptr[dst], e1 = row_ptr[dst + 1];
        int e = e0;
        for (; e + 4 <= e1; e += 4) {
            const unsigned short* p0 = base + (long long)col[e + 0] * CIN + c0;
            const unsigned short* p1 = base + (long long)col[e + 1] * CIN + c0;
            const unsigned short* p2 = base + (long long)col[e + 2] * CIN + c0;
            const unsigned short* p3 = base + (long long)col[e + 3] * CIN + c0;
            float n0 = wnorm[e + 0], n1 = wnorm[e + 1], n2 = wnorm[e + 2], n3 = wnorm[e + 3];
            short8 b0[NL], b1[NL], b2[NL], b3[NL];
#pragma unroll
            for (int l = 0; l < NL; ++l) b0[l] = ((const short8*)p0)[l];
#pragma unroll
            for (int l = 0; l < NL; ++l) b1[l] = ((const short8*)p1)[l];
#pragma unroll
            for (int l = 0; l < NL; ++l) b2[l] = ((const short8*)p2)[l];
#pragma unroll
            for (int l = 0; l < NL; ++l) b3[l] = ((const short8*)p3)[l];
            apply(b0, n0); apply(b1, n1); apply(b2, n2); apply(b3, n3);
        }
        for (; e < e1; ++e) {
            const unsigned short* p0 = base + (long long)col[e] * CIN + c0;
#pragma unroll
            for (int l = 0; l < NL; ++l) buf[l] = ((const short8*)p0)[l];
            apply(buf, wnorm[e]);
        }
    }
#pragma unroll
    for (int l = 0; l < NL; ++l) {
        short8 o;
#pragma unroll
        for (int q = 0; q < 8; ++q) o[q] = (short)f2b(acc[l * 8 + q]);
        *(short8*)&As[r * LDW + c0 + l * 8] = o;
    }
    __syncthreads();

    // ---- MFMA phase ----
    int lane = t & 63;
    int wave = t >> 6;
    int quad = lane >> 4;
    int l15  = lane & 15;
    f32x4 c4[MT][4];
#pragma unroll
    for (int mt = 0; mt < MT; ++mt)
#pragma unroll
        for (int nt = 0; nt < 4; ++nt) c4[mt][nt] = (f32x4){0.f, 0.f, 0.f, 0.f};

#pragma unroll
    for (int kb = 0; kb < CIN / 32; ++kb) {
        short8 af[MT];
#pragma unroll
        for (int mt = 0; mt < MT; ++mt)
            af[mt] = *(const short8*)&As[(mt * 16 + l15) * LDW + kb * 32 + quad * 8];
#pragma unroll
        for (int nt = 0; nt < 4; ++nt) {
            int nn = wave * 64 + nt * 16 + l15;
            short8 bf = *(const short8*)(Wz + ((size_t)(kb * 256 + nn) * 4 + quad) * 8);
#pragma unroll
            for (int mt = 0; mt < MT; ++mt)
                c4[mt][nt] = __builtin_amdgcn_mfma_f32_16x16x32_bf16(af[mt], bf, c4[mt][nt], 0, 0, 0);
        }
    }

    // epilogue: store + per-channel stat partials
    unsigned short* out = (unsigned short*)Anext;
#pragma unroll
    for (int nt = 0; nt < 4; ++nt) {
        int nn = wave * 64 + nt * 16 + l15;
        float bb = bias[nn];
        float s1p = 0.f, s2p = 0.f;
#pragma unroll
        for (int mt = 0; mt < MT; ++mt)
#pragma unroll
            for (int reg = 0; reg < 4; ++reg) {
                long long m = row0 + mt * 16 + quad * 4 + reg;
                if (m < n) {
                    float v = c4[mt][nt][reg] + bb;
                    out[m * 256 + nn] = f2b(v);
                    s1p += v;
                    s2p += v * v;
                }
            }
        s1p += __shfl_xor(s1p, 16); s1p += __shfl_xor(s1p, 32);
        s2p += __shfl_xor(s2p, 16); s2p += __shfl_xor(s2p, 32);
        if (quad == 0) {
            part1[(size_t)blockIdx.x * 256 + nn] = s1p;
            part2[(size_t)blockIdx.x * 256 + nn] = s2p;
        }
    }
}

// ---------------- stats partial reduction + finalize ----------------

__global__ void reduce_stats(int nblocks, int C, const float* __restrict__ part1,
                             const float* __restrict__ part2,
                             float* __restrict__ s1, float* __restrict__ s2) {
    int t = threadIdx.x;   // blockDim.x == C
    float a = 0.f, b = 0.f;
    for (int bi = blockIdx.x; bi < nblocks; bi += gridDim.x) {
        a += part1[(size_t)bi * C + t];
        b += part2[(size_t)bi * C + t];
    }
    atomicAdd(&s1[t], a);
    atomicAdd(&s2[t], b);
}

// reads s1/s2, writes scale/shift, then self-zeros s1/s2 for the next layer
__global__ void bn_finalize(float* __restrict__ s1, float* __restrict__ s2,
                            const float* __restrict__ g, const float* __restrict__ be,
                            float inv_n, float* __restrict__ scale, float* __restrict__ shift,
                            int C) {
    int c = blockIdx.x * blockDim.x + threadIdx.x;
    if (c >= C) return;
    float mean = s1[c] * inv_n;
    float var  = s2[c] * inv_n - mean * mean;
    float inv  = rsqrtf(var + BN_EPS);
    float sc   = g[c] * inv;
    scale[c] = sc;
    shift[c] = fmaf(-mean, sc, be[c]);
    s1[c] = 0.f;
    s2[c] = 0.f;
}

// ---------------- pooling: vectorized segmented mean (bf16 out) ----------------
// block = graph; 4 waves own rows i = s0+sr, s0+sr+4, ...; each lane owns 4 channels.

__global__ __launch_bounds__(256) void pool_graph(int G, const int* __restrict__ gstart,
                                                  const __hip_bfloat16* __restrict__ A,
                                                  const float* __restrict__ scale,
                                                  const float* __restrict__ shift,
                                                  unsigned short* __restrict__ pooled) {
    __shared__ float red[4 * 256];
    int g = blockIdx.x;
    int t = threadIdx.x;
    int sr = t >> 6;
    int c4 = (t & 63) * 4;
    int s0 = gstart[g], s1 = gstart[g + 1];
    float4 sc = *(const float4*)(scale + c4);
    float4 sh = *(const float4*)(shift + c4);
    const unsigned short* AA = (const unsigned short*)A;
    float a0 = 0.f, a1 = 0.f, a2 = 0.f, a3 = 0.f;
    int i = s0 + sr;
    for (; i + 4 < s1; i += 8) {          // 2 outstanding loads
        ushort4 u = *(const ushort4*)(AA + (size_t)i * 256 + c4);
        ushort4 w = *(const ushort4*)(AA + (size_t)(i + 4) * 256 + c4);
        a0 += fmaxf(fmaf(b2f(u.x), sc.x, sh.x), 0.f);
        a1 += fmaxf(fmaf(b2f(u.y), sc.y, sh.y), 0.f);
        a2 += fmaxf(fmaf(b2f(u.z), sc.z, sh.z), 0.f);
        a3 += fmaxf(fmaf(b2f(u.w), sc.w, sh.w), 0.f);
        a0 += fmaxf(fmaf(b2f(w.x), sc.x, sh.x), 0.f);
        a1 += fmaxf(fmaf(b2f(w.y), sc.y, sh.y), 0.f);
        a2 += fmaxf(fmaf(b2f(w.z), sc.z, sh.z), 0.f);
        a3 += fmaxf(fmaf(b2f(w.w), sc.w, sh.w), 0.f);
    }
    if (i < s1) {
        ushort4 u = *(const ushort4*)(AA + (size_t)i * 256 + c4);
        a0 += fmaxf(fmaf(b2f(u.x), sc.x, sh.x), 0.f);
        a1 += fmaxf(fmaf(b2f(u.y), sc.y, sh.y), 0.f);
        a2 += fmaxf(fmaf(b2f(u.z), sc.z, sh.z), 0.f);
        a3 += fmaxf(fmaf(b2f(u.w), sc.w, sh.w), 0.f);
    }
    red[sr * 256 + c4 + 0] = a0;
    red[sr * 256 + c4 + 1] = a1;
    red[sr * 256 + c4 + 2] = a2;
    red[sr * 256 + c4 + 3] = a3;
    __syncthreads();
    float inv = 1.0f / fmaxf((float)(s1 - s0), 1.0f);
    float s = red[t] + red[256 + t] + red[512 + t] + red[768 + t];
    pooled[(size_t)g * 256 + t] = f2b(s * inv);
}

// ---------------- final projection: MFMA (pooled bf16 @ Wp bf16 + bias, f32 out) ----------------

__global__ __launch_bounds__(256) void gemm_proj_mfma(
    int n, const unsigned short* __restrict__ pooled, const unsigned short* __restrict__ Wzp,
    const float* __restrict__ bias, float* __restrict__ out) {
    int t = threadIdx.x;
    long long row0 = (long long)blockIdx.x * 16;
    int lane = t & 63;
    int wave = t >> 6;
    int quad = lane >> 4;
    int l15  = lane & 15;
    f32x4 c4[4];
#pragma unroll
    for (int nt = 0; nt < 4; ++nt) c4[nt] = (f32x4){0.f, 0.f, 0.f, 0.f};
    long long arow = row0 + l15;
    bool av = arow < n;
#pragma unroll
    for (int kb = 0; kb < 8; ++kb) {
        short8 af = av ? *(const short8*)(pooled + arow * 256 + kb * 32 + quad * 8)
                       : (short8){0, 0, 0, 0, 0, 0, 0, 0};
#pragma unroll
        for (int nt = 0; nt < 4; ++nt) {
            int nn = wave * 64 + nt * 16 + l15;
            short8 bf = *(const short8*)(Wzp + ((size_t)(kb * 256 + nn) * 4 + quad) * 8);
            c4[nt] = __builtin_amdgcn_mfma_f32_16x16x32_bf16(af, bf, c4[nt], 0, 0, 0);
        }
    }
#pragma unroll
    for (int nt = 0; nt < 4; ++nt) {
        int nn = wave * 64 + nt * 16 + l15;
        float bb = bias[nn];
#pragma unroll
        for (int reg = 0; reg < 4; ++reg) {
            long long m = row0 + quad * 4 + reg;
            if (m < n) out[m * 256 + nn] = c4[nt][reg] + bb;
        }
    }
}

// ---------------- pipeline ----------------

static inline unsigned nblk(long long tot, int b) { return (unsigned)((tot + b - 1) / b); }
static inline size_t al256(size_t x) { return (x + 255) & ~(size_t)255; }
static inline size_t maxsz(size_t a, size_t b) { return a > b ? a : b; }

static size_t part_elems(int N) {
    return (size_t)nblk(N, 16) * 256;   // max over all producers
}

static size_t ws_need(int N, int E, int G) {
    size_t s = 0;
    s += 2 * al256((size_t)N * 256 * sizeof(__hip_bfloat16));  // A0, A1
    s += al256((size_t)N * sizeof(float));                     // dis
    s += 4 * al256((size_t)(N + 1) * sizeof(int));             // degc, ex, row_ptr, cursor
    s += al256((size_t)E * sizeof(int));                       // col
    s += al256((size_t)E * sizeof(float));                     // wnorm
    s += 2 * al256(1024 * sizeof(int));                        // bsum, boff
    s += 4 * al256(256 * sizeof(float));                       // s1, s2, scale, shift
    s += al256((size_t)(G + 1) * sizeof(int));                 // gstart
    s += al256(maxsz(2 * part_elems(N) * sizeof(float),
                     (size_t)G * 256 * sizeof(unsigned short)));  // parts | pooled
    s += al256((size_t)128 * 256 * 2) + 2 * al256((size_t)256 * 256 * 2);  // Wz2, Wz3, Wzp
    return s;
}

extern "C" void kernel_launch(void* const* d_in, const int* in_sizes, int n_in,
                              void* d_out, int out_size, void* d_ws, size_t ws_size,
                              hipStream_t stream) {
    const float* x     = (const float*)d_in[0];
    const int*   ei    = (const int*)d_in[1];   // integer inputs are int32
    const int*   batch = (const int*)d_in[2];
    const float* W1 = (const float*)d_in[4];
    const float* b1 = (const float*)d_in[5];
    const float* g1 = (const float*)d_in[6];
    const float* be1= (const float*)d_in[7];
    const float* W2 = (const float*)d_in[8];
    const float* b2 = (const float*)d_in[9];
    const float* g2 = (const float*)d_in[10];
    const float* be2= (const float*)d_in[11];
    const float* W3 = (const float*)d_in[12];
    const float* b3 = (const float*)d_in[13];
    const float* g3 = (const float*)d_in[14];
    const float* be3= (const float*)d_in[15];
    const float* Wp = (const float*)d_in[16];
    const float* bp = (const float*)d_in[17];

    const int N = in_sizes[0] / 9;
    const int E = in_sizes[1] / 2;
    const int G = out_size / 256;

    if (ws_size < ws_need(N, E, G)) {
        zero_f32<<<nblk(out_size, 256), 256, 0, stream>>>(out_size, (float*)d_out);
        return;
    }

    char* ws = (char*)d_ws;
    __hip_bfloat16* A0 = (__hip_bfloat16*)ws;  ws += al256((size_t)N * 256 * 2);
    __hip_bfloat16* A1 = (__hip_bfloat16*)ws;  ws += al256((size_t)N * 256 * 2);
    float* dis     = (float*)ws;  ws += al256((size_t)N * sizeof(float));
    int*   degc    = (int*)ws;    ws += al256((size_t)(N + 1) * sizeof(int));
    int*   ex      = (int*)ws;    ws += al256((size_t)(N + 1) * sizeof(int));
    int*   row_ptr = (int*)ws;    ws += al256((size_t)(N + 1) * sizeof(int));
    int*   cursor  = (int*)ws;    ws += al256((size_t)(N + 1) * sizeof(int));
    int*   col     = (int*)ws;    ws += al256((size_t)E * sizeof(int));
    float* wnorm   = (float*)ws;  ws += al256((size_t)E * sizeof(float));
    int*   bsum    = (int*)ws;    ws += al256(1024 * sizeof(int));
    int*   boff    = (int*)ws;    ws += al256(1024 * sizeof(int));
    float* s1      = (float*)ws;  ws += al256(256 * sizeof(float));
    float* s2      = (float*)ws;  ws += al256(256 * sizeof(float));
    float* scale   = (float*)ws;  ws += al256(256 * sizeof(float));
    float* shift   = (float*)ws;  ws += al256(256 * sizeof(float));
    int*   gstart  = (int*)ws;    ws += al256((size_t)(G + 1) * sizeof(int));
    size_t pe = part_elems(N);
    float* ureg    = (float*)ws;
    ws += al256(maxsz(2 * pe * sizeof(float), (size_t)G * 256 * sizeof(unsigned short)));
    float* part1   = ureg;
    float* part2   = ureg + pe;
    unsigned short* pooled = (unsigned short*)ureg;   // alias: parts dead before pooling
    unsigned short* Wz2 = (unsigned short*)ws;  ws += al256((size_t)128 * 256 * 2);
    unsigned short* Wz3 = (unsigned short*)ws;  ws += al256((size_t)256 * 256 * 2);
    unsigned short* Wzp = (unsigned short*)ws;

    int nb   = (N + 255) / 256;   // <= 1024
    int nb16 = nblk(N, 16);
    int nb32 = nblk(N, 32);

    // ---- setup + CSR ----
    setup_zero<<<nblk(N + 1, 256), 256, 0, stream>>>(N, degc, s1, s2);
    count_deg<<<nblk(E, 256), 256, 0, stream>>>(E, N, ei, degc);
    scan_block<<<nb, 256, 0, stream>>>(N, degc, ex, bsum);
    scan_sums<<<1, 1024, 0, stream>>>(nb, bsum, boff);
    finalize_rowptr<<<nblk(N + 1, 256), 256, 0, stream>>>(N, nb, ex, boff, bsum, degc,
                                                          row_ptr, cursor, dis);
    scatter_edges<<<nblk(E, 256), 256, 0, stream>>>(E, N, ei, dis, cursor, col, wnorm);
    graph_starts<<<nblk(N + 1, 256), 256, 0, stream>>>(N, G, batch, gstart);
    swizzle_all<<<nblk(20480, 256), 256, 0, stream>>>(W2, Wz2, W3, Wz3, Wp, Wzp);

    // ---- layer 1: fused gather + GEMM 9->128 + stat partials ----
    gemm9_fused<<<nb16, 256, 0, stream>>>(N, row_ptr, col, wnorm, dis, x, W1, b1, A0, part1, part2);
    reduce_stats<<<64, 128, 0, stream>>>(nb16, 128, part1, part2, s1, s2);
    bn_finalize<<<1, 128, 0, stream>>>(s1, s2, g1, be1, 1.0f / N, scale, shift, 128);

    // ---- layer 2: fused gather-agg(bnrelu(A0)) + MFMA 128->256 -> A1 ----
    fused_agg_gemm_mfma<128, 32><<<nb32, 256, 0, stream>>>(
        N, row_ptr, col, wnorm, dis, A0, scale, shift, Wz2, b2, A1, part1, part2);
    reduce_stats<<<64, 256, 0, stream>>>(nb32, 256, part1, part2, s1, s2);
    bn_finalize<<<1, 256, 0, stream>>>(s1, s2, g2, be2, 1.0f / N, scale, shift, 256);

    // ---- layer 3: fused gather-agg(bnrelu(A1)) + MFMA 256->256 -> A0 ----
    fused_agg_gemm_mfma<256, 16><<<nb16, 256, 0, stream>>>(
        N, row_ptr, col, wnorm, dis, A1, scale, shift, Wz3, b3, A0, part1, part2);
    reduce_stats<<<64, 256, 0, stream>>>(nb16, 256, part1, part2, s1, s2);
    bn_finalize<<<1, 256, 0, stream>>>(s1, s2, g3, be3, 1.0f / N, scale, shift, 256);

    // ---- global mean pool (bf16) + MFMA projection ----
    pool_graph<<<G, 256, 0, stream>>>(G, gstart, A0, scale, shift, pooled);
    gemm_proj_mfma<<<nblk(G, 16), 256, 0, stream>>>(G, pooled, Wzp, bp, (float*)d_out);
}

// Round 9
// 706.380 us; speedup vs baseline: 1.0425x; 1.0425x over previous
//
#include <hip/hip_runtime.h>
#include <hip/hip_bf16.h>

#define BN_EPS 1e-5f

typedef __attribute__((ext_vector_type(8))) short short8;
typedef __attribute__((ext_vector_type(4))) float f32x4;

__device__ __forceinline__ float bits2f(unsigned int u) {
    union { unsigned int i; float f; } c; c.i = u; return c.f;
}
__device__ __forceinline__ float b2f(unsigned short u) { return bits2f(((unsigned int)u) << 16); }
__device__ __forceinline__ unsigned short f2b(float v) {
    __hip_bfloat16 h = __float2bfloat16(v);
    union { __hip_bfloat16 h; unsigned short u; } c; c.h = h; return c.u;
}
__device__ __forceinline__ int clampi(int v, int hi) {
    return v < 0 ? 0 : (v >= hi ? hi - 1 : v);
}

// ---------------- setup / zero ----------------

__global__ void zero_f32(long long n, float* __restrict__ p) {
    long long i = (long long)blockIdx.x * blockDim.x + threadIdx.x;
    if (i < n) p[i] = 0.f;
}

__global__ void setup_zero(int N, int* __restrict__ degc, float* __restrict__ s1,
                           float* __restrict__ s2) {
    int i = blockIdx.x * blockDim.x + threadIdx.x;
    if (i <= N) degc[i] = 0;
    if (i < 256) { s1[i] = 0.f; s2[i] = 0.f; }
}

// ---------------- degree / CSR construction ----------------

__global__ void count_deg(int E, int N, const int* __restrict__ ei, int* __restrict__ degc) {
    int e = blockIdx.x * blockDim.x + threadIdx.x;
    if (e >= E) return;
    atomicAdd(&degc[clampi(ei[(size_t)E + e], N)], 1);
}

__global__ __launch_bounds__(256) void scan_block(int N, const int* __restrict__ cnts,
                                                  int* __restrict__ ex, int* __restrict__ bsum) {
    __shared__ int s[256];
    int t = threadIdx.x;
    int i = blockIdx.x * 256 + t;
    int v = (i < N) ? cnts[i] : 0;
    s[t] = v;
    __syncthreads();
    for (int o = 1; o < 256; o <<= 1) {
        int add = (t >= o) ? s[t - o] : 0;
        __syncthreads();
        s[t] += add;
        __syncthreads();
    }
    if (i < N) ex[i] = s[t] - v;
    if (t == 255) bsum[blockIdx.x] = s[255];
}

__global__ __launch_bounds__(1024) void scan_sums(int nb, const int* __restrict__ bsum,
                                                  int* __restrict__ boff) {
    __shared__ int s[1024];
    int t = threadIdx.x;
    int v = (t < nb) ? bsum[t] : 0;
    s[t] = v;
    __syncthreads();
    for (int o = 1; o < 1024; o <<= 1) {
        int add = (t >= o) ? s[t - o] : 0;
        __syncthreads();
        s[t] += add;
        __syncthreads();
    }
    if (t < nb) boff[t] = s[t] - v;
}

// also computes dis[i] = rsqrt(deg+1)
__global__ void finalize_rowptr(int N, int nb, const int* __restrict__ ex,
                                const int* __restrict__ boff, const int* __restrict__ bsum,
                                const int* __restrict__ degc,
                                int* __restrict__ row_ptr, int* __restrict__ cursor,
                                float* __restrict__ dis) {
    int i = blockIdx.x * blockDim.x + threadIdx.x;
    if (i < N) {
        int v = ex[i] + boff[i >> 8];
        row_ptr[i] = v;
        cursor[i]  = v;
        dis[i] = rsqrtf((float)degc[i] + 1.0f);
    } else if (i == N) {
        row_ptr[N] = boff[nb - 1] + bsum[nb - 1];
    }
}

__global__ void scatter_edges(int E, int N, const int* __restrict__ ei, const float* __restrict__ dis,
                              int* __restrict__ cursor, int* __restrict__ col,
                              float* __restrict__ wnorm) {
    int e = blockIdx.x * blockDim.x + threadIdx.x;
    if (e >= E) return;
    int s = clampi(ei[e], N);
    int d = clampi(ei[(size_t)E + e], N);
    int pos = atomicAdd(&cursor[d], 1);
    col[pos]   = s;
    wnorm[pos] = dis[s] * dis[d];
}

// ---------------- graph segment starts from sorted batch ----------------

__global__ void graph_starts(int N, int G, const int* __restrict__ batch, int* __restrict__ gstart) {
    int i = blockIdx.x * blockDim.x + threadIdx.x;
    if (i > N) return;
    int curr = (i < N) ? clampi(batch[i], G) : G;
    int prev = (i > 0) ? clampi(batch[i - 1], G) : -1;
    for (int g = prev + 1; g <= curr; ++g) gstart[g] = i;
}

// ---------------- merged W swizzles (B-fragment order, bf16) ----------------

__device__ __forceinline__ void swz_one(int idx, const float* __restrict__ W,
                                        unsigned short* __restrict__ Wz) {
    int quad = idx & 3;
    int n    = (idx >> 2) & 255;
    int kb   = idx >> 10;
    unsigned short o[8];
#pragma unroll
    for (int j = 0; j < 8; ++j)
        o[j] = f2b(W[(size_t)(kb * 32 + quad * 8 + j) * 256 + n]);
    ushort4* dst = (ushort4*)(Wz + (size_t)idx * 8);
    dst[0] = make_ushort4(o[0], o[1], o[2], o[3]);
    dst[1] = make_ushort4(o[4], o[5], o[6], o[7]);
}

__global__ void swizzle_all(const float* __restrict__ W2, unsigned short* __restrict__ Wz2,
                            const float* __restrict__ W3, unsigned short* __restrict__ Wz3,
                            const float* __restrict__ Wp, unsigned short* __restrict__ Wzp) {
    int idx = blockIdx.x * blockDim.x + threadIdx.x;
    if (idx < 4096)        swz_one(idx, W2, Wz2);
    else if (idx < 12288)  swz_one(idx - 4096, W3, Wz3);
    else if (idx < 20480)  swz_one(idx - 12288, Wp, Wzp);
}

// ---------------- layer 1: fused CSR gather (9 ch) + GEMM 9->128 + stats ----------------

__global__ __launch_bounds__(256) void gemm9_fused(
    int n, const int* __restrict__ row_ptr, const int* __restrict__ col,
    const float* __restrict__ wnorm, const float* __restrict__ dis,
    const float* __restrict__ x, const float* __restrict__ W, const float* __restrict__ bias,
    __hip_bfloat16* __restrict__ y, float* __restrict__ part1, float* __restrict__ part2) {
    __shared__ float sW[9 * 128];
    __shared__ float sA[16 * 9];
    __shared__ float lds1[256];
    __shared__ float lds2[256];
    int t = threadIdx.x;
    long long row0 = (long long)blockIdx.x * 16;
    for (int idx = t; idx < 9 * 128; idx += 256) sW[idx] = W[idx];
    if (t < 144) {
        int r = t / 9;
        int k = t - r * 9;
        long long row = row0 + r;
        float a = 0.f;
        if (row < n) {
            float dd = dis[row];
            a = dd * dd * x[row * 9 + k];
            int e0 = row_ptr[row], e1 = row_ptr[row + 1];
            for (int e = e0; e < e1; ++e)
                a = fmaf(wnorm[e], x[(long long)col[e] * 9 + k], a);
        }
        sA[r * 9 + k] = a;
    }
    __syncthreads();
    int ch   = t & 127;
    int half = t >> 7;
    float bb = bias[ch];
    float s1p = 0.f, s2p = 0.f;
#pragma unroll
    for (int r8 = 0; r8 < 8; ++r8) {
        int r = half * 8 + r8;
        long long row = row0 + r;
        float acc = bb;
#pragma unroll
        for (int k = 0; k < 9; ++k) acc = fmaf(sA[r * 9 + k], sW[k * 128 + ch], acc);
        if (row < n) {
            y[row * 128 + ch] = __float2bfloat16(acc);
            s1p += acc;
            s2p += acc * acc;
        }
    }
    lds1[t] = s1p; lds2[t] = s2p;
    __syncthreads();
    if (t < 128) {
        part1[(size_t)blockIdx.x * 128 + t] = lds1[t] + lds1[t + 128];
        part2[(size_t)blockIdx.x * 128 + t] = lds2[t] + lds2[t + 128];
    }
}

// ---------------- fused CSR-gather + MFMA GEMM (Cout=256) + stats ----------------
// Round-6 empirically-best config: R=16 rows/block, 16 threads/row, EPT=CIN/16,
// edge loop unrolled x2 -> VGPR ~56, occupancy ~42% (the latency-hiding sweet spot).

template<int CIN>
__global__ __launch_bounds__(256) void fused_agg_gemm_mfma(
    int n, const int* __restrict__ row_ptr, const int* __restrict__ col,
    const float* __restrict__ wnorm, const float* __restrict__ dis,
    const __hip_bfloat16* __restrict__ Aprev,
    const float* __restrict__ scale, const float* __restrict__ shift,
    const unsigned short* __restrict__ Wz, const float* __restrict__ bias,
    __hip_bfloat16* __restrict__ Anext,
    float* __restrict__ part1, float* __restrict__ part2) {
    constexpr int R   = 16;
    constexpr int EPT = CIN / 16;         // 8 (CIN=128) or 16 (CIN=256)
    constexpr int NL  = EPT / 8;          // 1 or 2
    constexpr int LDW = CIN + 8;
    __shared__ unsigned short As[R * LDW];
    __shared__ float ssc[CIN];
    __shared__ float ssh[CIN];
    int t = threadIdx.x;
    for (int c = t; c < CIN; c += 256) { ssc[c] = scale[c]; ssh[c] = shift[c]; }
    __syncthreads();

    int r   = t >> 4;
    int t16 = t & 15;
    int c0  = t16 * EPT;
    long long row0 = (long long)blockIdx.x * R;
    long long dst  = row0 + r;

    float acc[EPT];
#pragma unroll
    for (int j = 0; j < EPT; ++j) acc[j] = 0.f;

    const unsigned short* base = (const unsigned short*)Aprev;

    if (dst < n) {
        auto apply = [&](const short8* b, float nm) {
#pragma unroll
            for (int l = 0; l < NL; ++l)
#pragma unroll
                for (int q = 0; q < 8; ++q) {
                    int j = l * 8 + q;
                    float v = b2f((unsigned short)b[l][q]);
                    acc[j] = fmaf(nm, fmaxf(fmaf(v, ssc[c0 + j], ssh[c0 + j]), 0.f), acc[j]);
                }
        };
        short8 buf[NL];
        {
            const unsigned short* ap = base + dst * CIN + c0;
#pragma unroll
            for (int l = 0; l < NL; ++l) buf[l] = ((const short8*)ap)[l];
            float dd = dis[dst];
            apply(buf, dd * dd);
        }
        int e0 = row_ptr[dst], e1 = row_ptr[dst + 1];
        int e = e0;
        for (; e + 2 <= e1; e += 2) {
            const unsigned short* pA = base + (long long)col[e + 0] * CIN + c0;
            const unsigned short* pB = base + (long long)col[e + 1] * CIN + c0;
            float na = wnorm[e + 0], nb = wnorm[e + 1];
            short8 bufA[NL], bufB[NL];
#pragma unroll
            for (int l = 0; l < NL; ++l) bufA[l] = ((const short8*)pA)[l];
#pragma unroll
            for (int l = 0; l < NL; ++l) bufB[l] = ((const short8*)pB)[l];
            apply(bufA, na);
            apply(bufB, nb);
        }
        if (e < e1) {
            const unsigned short* pA = base + (long long)col[e] * CIN + c0;
#pragma unroll
            for (int l = 0; l < NL; ++l) buf[l] = ((const short8*)pA)[l];
            apply(buf, wnorm[e]);
        }
    }
#pragma unroll
    for (int l = 0; l < NL; ++l) {
        short8 o;
#pragma unroll
        for (int q = 0; q < 8; ++q) o[q] = (short)f2b(acc[l * 8 + q]);
        *(short8*)&As[r * LDW + c0 + l * 8] = o;
    }
    __syncthreads();

    // ---- MFMA phase: 1 m-tile x 4 n-tiles per wave ----
    int lane = t & 63;
    int wave = t >> 6;
    int quad = lane >> 4;
    int l15  = lane & 15;
    f32x4 c4[4];
#pragma unroll
    for (int nt = 0; nt < 4; ++nt) c4[nt] = (f32x4){0.f, 0.f, 0.f, 0.f};

#pragma unroll
    for (int kb = 0; kb < CIN / 32; ++kb) {
        short8 af = *(const short8*)&As[l15 * LDW + kb * 32 + quad * 8];
#pragma unroll
        for (int nt = 0; nt < 4; ++nt) {
            int nn = wave * 64 + nt * 16 + l15;
            short8 bf = *(const short8*)(Wz + ((size_t)(kb * 256 + nn) * 4 + quad) * 8);
            c4[nt] = __builtin_amdgcn_mfma_f32_16x16x32_bf16(af, bf, c4[nt], 0, 0, 0);
        }
    }

    // epilogue: store + per-channel stat partials (cross-quad shuffle reduce)
    unsigned short* out = (unsigned short*)Anext;
#pragma unroll
    for (int nt = 0; nt < 4; ++nt) {
        int nn = wave * 64 + nt * 16 + l15;
        float bb = bias[nn];
        float s1p = 0.f, s2p = 0.f;
#pragma unroll
        for (int reg = 0; reg < 4; ++reg) {
            long long m = row0 + quad * 4 + reg;
            if (m < n) {
                float v = c4[nt][reg] + bb;
                out[m * 256 + nn] = f2b(v);
                s1p += v;
                s2p += v * v;
            }
        }
        s1p += __shfl_xor(s1p, 16); s1p += __shfl_xor(s1p, 32);
        s2p += __shfl_xor(s2p, 16); s2p += __shfl_xor(s2p, 32);
        if (quad == 0) {
            part1[(size_t)blockIdx.x * 256 + nn] = s1p;
            part2[(size_t)blockIdx.x * 256 + nn] = s2p;
        }
    }
}

// ---------------- stats partial reduction + finalize ----------------

__global__ void reduce_stats(int nblocks, int C, const float* __restrict__ part1,
                             const float* __restrict__ part2,
                             float* __restrict__ s1, float* __restrict__ s2) {
    int t = threadIdx.x;   // blockDim.x == C
    float a = 0.f, b = 0.f;
    for (int bi = blockIdx.x; bi < nblocks; bi += gridDim.x) {
        a += part1[(size_t)bi * C + t];
        b += part2[(size_t)bi * C + t];
    }
    atomicAdd(&s1[t], a);
    atomicAdd(&s2[t], b);
}

// reads s1/s2, writes scale/shift, then self-zeros s1/s2 for the next layer
__global__ void bn_finalize(float* __restrict__ s1, float* __restrict__ s2,
                            const float* __restrict__ g, const float* __restrict__ be,
                            float inv_n, float* __restrict__ scale, float* __restrict__ shift,
                            int C) {
    int c = blockIdx.x * blockDim.x + threadIdx.x;
    if (c >= C) return;
    float mean = s1[c] * inv_n;
    float var  = s2[c] * inv_n - mean * mean;
    float inv  = rsqrtf(var + BN_EPS);
    float sc   = g[c] * inv;
    scale[c] = sc;
    shift[c] = fmaf(-mean, sc, be[c]);
    s1[c] = 0.f;
    s2[c] = 0.f;
}

// ---------------- pooling: vectorized segmented mean (bf16 out) ----------------

__global__ __launch_bounds__(256) void pool_graph(int G, const int* __restrict__ gstart,
                                                  const __hip_bfloat16* __restrict__ A,
                                                  const float* __restrict__ scale,
                                                  const float* __restrict__ shift,
                                                  unsigned short* __restrict__ pooled) {
    __shared__ float red[4 * 256];
    int g = blockIdx.x;
    int t = threadIdx.x;
    int sr = t >> 6;
    int c4 = (t & 63) * 4;
    int s0 = gstart[g], s1 = gstart[g + 1];
    float4 sc = *(const float4*)(scale + c4);
    float4 sh = *(const float4*)(shift + c4);
    const unsigned short* AA = (const unsigned short*)A;
    float a0 = 0.f, a1 = 0.f, a2 = 0.f, a3 = 0.f;
    int i = s0 + sr;
    for (; i + 4 < s1; i += 8) {
        ushort4 u = *(const ushort4*)(AA + (size_t)i * 256 + c4);
        ushort4 w = *(const ushort4*)(AA + (size_t)(i + 4) * 256 + c4);
        a0 += fmaxf(fmaf(b2f(u.x), sc.x, sh.x), 0.f);
        a1 += fmaxf(fmaf(b2f(u.y), sc.y, sh.y), 0.f);
        a2 += fmaxf(fmaf(b2f(u.z), sc.z, sh.z), 0.f);
        a3 += fmaxf(fmaf(b2f(u.w), sc.w, sh.w), 0.f);
        a0 += fmaxf(fmaf(b2f(w.x), sc.x, sh.x), 0.f);
        a1 += fmaxf(fmaf(b2f(w.y), sc.y, sh.y), 0.f);
        a2 += fmaxf(fmaf(b2f(w.z), sc.z, sh.z), 0.f);
        a3 += fmaxf(fmaf(b2f(w.w), sc.w, sh.w), 0.f);
    }
    if (i < s1) {
        ushort4 u = *(const ushort4*)(AA + (size_t)i * 256 + c4);
        a0 += fmaxf(fmaf(b2f(u.x), sc.x, sh.x), 0.f);
        a1 += fmaxf(fmaf(b2f(u.y), sc.y, sh.y), 0.f);
        a2 += fmaxf(fmaf(b2f(u.z), sc.z, sh.z), 0.f);
        a3 += fmaxf(fmaf(b2f(u.w), sc.w, sh.w), 0.f);
    }
    red[sr * 256 + c4 + 0] = a0;
    red[sr * 256 + c4 + 1] = a1;
    red[sr * 256 + c4 + 2] = a2;
    red[sr * 256 + c4 + 3] = a3;
    __syncthreads();
    float inv = 1.0f / fmaxf((float)(s1 - s0), 1.0f);
    float s = red[t] + red[256 + t] + red[512 + t] + red[768 + t];
    pooled[(size_t)g * 256 + t] = f2b(s * inv);
}

// ---------------- final projection: MFMA (pooled bf16 @ Wp bf16 + bias, f32 out) ----------------

__global__ __launch_bounds__(256) void gemm_proj_mfma(
    int n, const unsigned short* __restrict__ pooled, const unsigned short* __restrict__ Wzp,
    const float* __restrict__ bias, float* __restrict__ out) {
    int t = threadIdx.x;
    long long row0 = (long long)blockIdx.x * 16;
    int lane = t & 63;
    int wave = t >> 6;
    int quad = lane >> 4;
    int l15  = lane & 15;
    f32x4 c4[4];
#pragma unroll
    for (int nt = 0; nt < 4; ++nt) c4[nt] = (f32x4){0.f, 0.f, 0.f, 0.f};
    long long arow = row0 + l15;
    bool av = arow < n;
#pragma unroll
    for (int kb = 0; kb < 8; ++kb) {
        short8 af = av ? *(const short8*)(pooled + arow * 256 + kb * 32 + quad * 8)
                       : (short8){0, 0, 0, 0, 0, 0, 0, 0};
#pragma unroll
        for (int nt = 0; nt < 4; ++nt) {
            int nn = wave * 64 + nt * 16 + l15;
            short8 bf = *(const short8*)(Wzp + ((size_t)(kb * 256 + nn) * 4 + quad) * 8);
            c4[nt] = __builtin_amdgcn_mfma_f32_16x16x32_bf16(af, bf, c4[nt], 0, 0, 0);
        }
    }
#pragma unroll
    for (int nt = 0; nt < 4; ++nt) {
        int nn = wave * 64 + nt * 16 + l15;
        float bb = bias[nn];
#pragma unroll
        for (int reg = 0; reg < 4; ++reg) {
            long long m = row0 + quad * 4 + reg;
            if (m < n) out[m * 256 + nn] = c4[nt][reg] + bb;
        }
    }
}

// ---------------- pipeline ----------------

static inline unsigned nblk(long long tot, int b) { return (unsigned)((tot + b - 1) / b); }
static inline size_t al256(size_t x) { return (x + 255) & ~(size_t)255; }
static inline size_t maxsz(size_t a, size_t b) { return a > b ? a : b; }

static size_t part_elems(int N) {
    return (size_t)nblk(N, 16) * 256;
}

static size_t ws_need(int N, int E, int G) {
    size_t s = 0;
    s += 2 * al256((size_t)N * 256 * sizeof(__hip_bfloat16));  // A0, A1
    s += al256((size_t)N * sizeof(float));                     // dis
    s += 4 * al256((size_t)(N + 1) * sizeof(int));             // degc, ex, row_ptr, cursor
    s += al256((size_t)E * sizeof(int));                       // col
    s += al256((size_t)E * sizeof(float));                     // wnorm
    s += 2 * al256(1024 * sizeof(int));                        // bsum, boff
    s += 4 * al256(256 * sizeof(float));                       // s1, s2, scale, shift
    s += al256((size_t)(G + 1) * sizeof(int));                 // gstart
    s += al256(maxsz(2 * part_elems(N) * sizeof(float),
                     (size_t)G * 256 * sizeof(unsigned short)));  // parts | pooled
    s += al256((size_t)128 * 256 * 2) + 2 * al256((size_t)256 * 256 * 2);  // Wz2, Wz3, Wzp
    return s;
}

extern "C" void kernel_launch(void* const* d_in, const int* in_sizes, int n_in,
                              void* d_out, int out_size, void* d_ws, size_t ws_size,
                              hipStream_t stream) {
    const float* x     = (const float*)d_in[0];
    const int*   ei    = (const int*)d_in[1];   // integer inputs are int32
    const int*   batch = (const int*)d_in[2];
    const float* W1 = (const float*)d_in[4];
    const float* b1 = (const float*)d_in[5];
    const float* g1 = (const float*)d_in[6];
    const float* be1= (const float*)d_in[7];
    const float* W2 = (const float*)d_in[8];
    const float* b2 = (const float*)d_in[9];
    const float* g2 = (const float*)d_in[10];
    const float* be2= (const float*)d_in[11];
    const float* W3 = (const float*)d_in[12];
    const float* b3 = (const float*)d_in[13];
    const float* g3 = (const float*)d_in[14];
    const float* be3= (const float*)d_in[15];
    const float* Wp = (const float*)d_in[16];
    const float* bp = (const float*)d_in[17];

    const int N = in_sizes[0] / 9;
    const int E = in_sizes[1] / 2;
    const int G = out_size / 256;

    if (ws_size < ws_need(N, E, G)) {
        zero_f32<<<nblk(out_size, 256), 256, 0, stream>>>(out_size, (float*)d_out);
        return;
    }

    char* ws = (char*)d_ws;
    __hip_bfloat16* A0 = (__hip_bfloat16*)ws;  ws += al256((size_t)N * 256 * 2);
    __hip_bfloat16* A1 = (__hip_bfloat16*)ws;  ws += al256((size_t)N * 256 * 2);
    float* dis     = (float*)ws;  ws += al256((size_t)N * sizeof(float));
    int*   degc    = (int*)ws;    ws += al256((size_t)(N + 1) * sizeof(int));
    int*   ex      = (int*)ws;    ws += al256((size_t)(N + 1) * sizeof(int));
    int*   row_ptr = (int*)ws;    ws += al256((size_t)(N + 1) * sizeof(int));
    int*   cursor  = (int*)ws;    ws += al256((size_t)(N + 1) * sizeof(int));
    int*   col     = (int*)ws;    ws += al256((size_t)E * sizeof(int));
    float* wnorm   = (float*)ws;  ws += al256((size_t)E * sizeof(float));
    int*   bsum    = (int*)ws;    ws += al256(1024 * sizeof(int));
    int*   boff    = (int*)ws;    ws += al256(1024 * sizeof(int));
    float* s1      = (float*)ws;  ws += al256(256 * sizeof(float));
    float* s2      = (float*)ws;  ws += al256(256 * sizeof(float));
    float* scale   = (float*)ws;  ws += al256(256 * sizeof(float));
    float* shift   = (float*)ws;  ws += al256(256 * sizeof(float));
    int*   gstart  = (int*)ws;    ws += al256((size_t)(G + 1) * sizeof(int));
    size_t pe = part_elems(N);
    float* ureg    = (float*)ws;
    ws += al256(maxsz(2 * pe * sizeof(float), (size_t)G * 256 * sizeof(unsigned short)));
    float* part1   = ureg;
    float* part2   = ureg + pe;
    unsigned short* pooled = (unsigned short*)ureg;   // alias: parts dead before pooling
    unsigned short* Wz2 = (unsigned short*)ws;  ws += al256((size_t)128 * 256 * 2);
    unsigned short* Wz3 = (unsigned short*)ws;  ws += al256((size_t)256 * 256 * 2);
    unsigned short* Wzp = (unsigned short*)ws;

    int nb   = (N + 255) / 256;   // <= 1024
    int nb16 = nblk(N, 16);

    // ---- setup + CSR ----
    setup_zero<<<nblk(N + 1, 256), 256, 0, stream>>>(N, degc, s1, s2);
    count_deg<<<nblk(E, 256), 256, 0, stream>>>(E, N, ei, degc);
    scan_block<<<nb, 256, 0, stream>>>(N, degc, ex, bsum);
    scan_sums<<<1, 1024, 0, stream>>>(nb, bsum, boff);
    finalize_rowptr<<<nblk(N + 1, 256), 256, 0, stream>>>(N, nb, ex, boff, bsum, degc,
                                                          row_ptr, cursor, dis);
    scatter_edges<<<nblk(E, 256), 256, 0, stream>>>(E, N, ei, dis, cursor, col, wnorm);
    graph_starts<<<nblk(N + 1, 256), 256, 0, stream>>>(N, G, batch, gstart);
    swizzle_all<<<nblk(20480, 256), 256, 0, stream>>>(W2, Wz2, W3, Wz3, Wp, Wzp);

    // ---- layer 1: fused gather + GEMM 9->128 + stat partials ----
    gemm9_fused<<<nb16, 256, 0, stream>>>(N, row_ptr, col, wnorm, dis, x, W1, b1, A0, part1, part2);
    reduce_stats<<<64, 128, 0, stream>>>(nb16, 128, part1, part2, s1, s2);
    bn_finalize<<<1, 128, 0, stream>>>(s1, s2, g1, be1, 1.0f / N, scale, shift, 128);

    // ---- layer 2: fused gather-agg(bnrelu(A0)) + MFMA 128->256 -> A1 ----
    fused_agg_gemm_mfma<128><<<nb16, 256, 0, stream>>>(
        N, row_ptr, col, wnorm, dis, A0, scale, shift, Wz2, b2, A1, part1, part2);
    reduce_stats<<<64, 256, 0, stream>>>(nb16, 256, part1, part2, s1, s2);
    bn_finalize<<<1, 256, 0, stream>>>(s1, s2, g2, be2, 1.0f / N, scale, shift, 256);

    // ---- layer 3: fused gather-agg(bnrelu(A1)) + MFMA 256->256 -> A0 ----
    fused_agg_gemm_mfma<256><<<nb16, 256, 0, stream>>>(
        N, row_ptr, col, wnorm, dis, A1, scale, shift, Wz3, b3, A0, part1, part2);
    reduce_stats<<<64, 256, 0, stream>>>(nb16, 256, part1, part2, s1, s2);
    bn_finalize<<<1, 256, 0, stream>>>(s1, s2, g3, be3, 1.0f / N, scale, shift, 256);

    // ---- global mean pool (bf16) + MFMA projection ----
    pool_graph<<<G, 256, 0, stream>>>(G, gstart, A0, scale, shift, pooled);
    gemm_proj_mfma<<<nblk(G, 16), 256, 0, stream>>>(G, pooled, Wzp, bp, (float*)d_out);
}